// Round 4
// baseline (276.642 us; speedup 1.0000x reference)
//
#include <hip/hip_runtime.h>
#include <math.h>

// Problem constants (match reference)
#define NB 2
#define NS 8
#define NA 24000
#define NC 80
#define NM 20
#define NCE 7
#define NBS (NB*NS)          // 16 frames
#define CPB 75               // chunks (blocks) per frame
#define APC (NA/CPB)         // anchors per chunk = 320

#define POS_TH 0.5f
#define NEG_TH 0.4f
#define OMB 1e-4f            // 1.0 - 0.9999 (correctly rounded to f32)

// k_cls geometry: 3000 blocks x 256 threads x 10 float4 = 7,680,000 f4 = NBS*NA*NC/4
#define CLS_BLOCKS 3000
#define CLS_F4_PER_BLOCK 2560    // = 128 anchors * 20 f4

// pack (iou, anchor_idx) into u64 so that max-reduce picks higher iou,
// tie -> smaller anchor index (argmax first-occurrence semantics)
__device__ inline unsigned long long packKey(float f, unsigned idx) {
    unsigned u = __float_as_uint(f);
    u = (u & 0x80000000u) ? ~u : (u | 0x80000000u);   // total order on floats
    return ((unsigned long long)u << 32) | (unsigned long long)(0xFFFFFFFFu - idx);
}

// non-temporal float4 load: no L2/L3 allocation -> fewer dirty-victim writebacks
typedef float v4f __attribute__((ext_vector_type(4)));
__device__ inline float4 ntload4(const float4* p) {
    v4f v = __builtin_nontemporal_load((const v4f*)p);
    return make_float4(v.x, v.y, v.z, v.w);
}

// ---------------- kernel 1: per-gt global best anchor via atomicMax ----------------
__global__ void __launch_bounds__(256)
k_gbest(const float* __restrict__ gtb, const int* __restrict__ counts,
        const float* __restrict__ anchors, unsigned long long* __restrict__ gbest) {
    int bid = blockIdx.x;
    int bs = bid / CPB;
    int chunk = bid % CPB;
    int t = threadIdx.x;
    int cnt = counts[bs];
    if (cnt == 0) return;                 // block-uniform: all threads exit together

    __shared__ float sg[NM][5];           // x1,y1,x2,y2,area (gt already point form)
    if (t < NM) {
        const float* g = gtb + ((size_t)bs * NM + t) * 4;
        float x1 = g[0], y1 = g[1], x2 = g[2], y2 = g[3];
        sg[t][0] = x1; sg[t][1] = y1; sg[t][2] = x2; sg[t][3] = y2;
        sg[t][4] = (x2 - x1) * (y2 - y1);
    }
    __syncthreads();

    int a0 = chunk * APC;
    // anchor 1: a0+t (all threads); anchor 2: a0+256+t (threads 0..63)
    bool has2 = t < (APC - 256);
    float4 c1 = ((const float4*)anchors)[a0 + t];
    float bx1 = c1.x - c1.z * 0.5f, by1 = c1.y - c1.w * 0.5f;
    float bx2 = c1.x + c1.z * 0.5f, by2 = c1.y + c1.w * 0.5f;
    float bar = (bx2 - bx1) * (by2 - by1);
    float cx1 = 0, cy1 = 0, cx2 = 0, cy2 = 0, car = 0;
    if (has2) {
        float4 c2 = ((const float4*)anchors)[a0 + 256 + t];
        cx1 = c2.x - c2.z * 0.5f; cy1 = c2.y - c2.w * 0.5f;
        cx2 = c2.x + c2.z * 0.5f; cy2 = c2.y + c2.w * 0.5f;
        car = (cx2 - cx1) * (cy2 - cy1);
    }

    __shared__ unsigned long long sk[4][NM];
    int wave = t >> 6, lane = t & 63;
    for (int m = 0; m < cnt; m++) {
        float gx1 = sg[m][0], gy1 = sg[m][1], gx2 = sg[m][2], gy2 = sg[m][3], gar = sg[m][4];
        float ltx = fmaxf(gx1, bx1), lty = fmaxf(gy1, by1);
        float rbx = fminf(gx2, bx2), rby = fminf(gy2, by2);
        float wx = fmaxf(rbx - ltx, 0.0f), wy = fmaxf(rby - lty, 0.0f);
        float inter = wx * wy;
        float iou = inter / (gar + bar - inter + 1e-10f);   // IEEE div: threshold-exact vs ref
        unsigned long long k = packKey(iou, (unsigned)(a0 + t));
        if (has2) {
            float ltx2 = fmaxf(gx1, cx1), lty2 = fmaxf(gy1, cy1);
            float rbx2 = fminf(gx2, cx2), rby2 = fminf(gy2, cy2);
            float wx2 = fmaxf(rbx2 - ltx2, 0.0f), wy2 = fmaxf(rby2 - lty2, 0.0f);
            float inter2 = wx2 * wy2;
            float iou2 = inter2 / (gar + car - inter2 + 1e-10f);
            unsigned long long k2 = packKey(iou2, (unsigned)(a0 + 256 + t));
            if (k2 > k) k = k2;
        }
        #pragma unroll
        for (int off = 32; off > 0; off >>= 1) {
            unsigned long long o = __shfl_xor(k, off);
            if (o > k) k = o;
        }
        if (lane == 0) sk[wave][m] = k;
    }
    __syncthreads();
    if (t < cnt) {
        unsigned long long k = sk[0][t];
        if (sk[1][t] > k) k = sk[1][t];
        if (sk[2][t] > k) k = sk[2][t];
        if (sk[3][t] > k) k = sk[3][t];
        atomicMax(&gbest[bs * NM + t], k);
    }
}

// ---------------- kernel 2: match resolve + regression + positive corrections ---------
// Phase A (per anchor): recompute best-gt IoU, resolve force-match from gbest, codes,
// write cmask to GLOBAL (for k_cls), regression loss, compact positives into LDS queue.
// Phase B: cooperative (divergence-free, coalesced) positive y==1 class corrections.
// Identities (e=exp(-x), s=1+e, p=1/s): -log(p)=log(s), -log(1-p)=x+log(s), 1-p=e*p.
__global__ void __launch_bounds__(256)
k_match(const float* __restrict__ gtb, const int* __restrict__ counts,
        const float* __restrict__ anchors, const float* __restrict__ ploc,
        const float* __restrict__ gtl, const float* __restrict__ logits,
        const int* __restrict__ cls_num,
        const unsigned long long* __restrict__ gbest,
        float* __restrict__ maskG,
        double* __restrict__ acc, int* __restrict__ npos) {
    int bid = blockIdx.x;
    int bs = bid / CPB;
    int chunk = bid % CPB;
    int t = threadIdx.x;
    int cnt = counts[bs];

    __shared__ float sg[NM][5];
    __shared__ unsigned abest[NM];
    __shared__ float wsh[NC];
    __shared__ float wsum_sh;
    __shared__ unsigned qpos[APC];   // compacted positives: (gt_idx<<16) | local_anchor
    __shared__ int npq;
    if (t == 0) npq = 0;
    if (t < NM) {
        const float* g = gtb + ((size_t)bs * NM + t) * 4;
        float x1 = g[0], y1 = g[1], x2 = g[2], y2 = g[3];
        sg[t][0] = x1; sg[t][1] = y1; sg[t][2] = x2; sg[t][3] = y2;
        sg[t][4] = (x2 - x1) * (y2 - y1);
        if (t < cnt)
            abest[t] = 0xFFFFFFFFu - (unsigned)(gbest[bs * NM + t] & 0xFFFFFFFFull);
    }
    // CB weights, computed redundantly per block (80 powf — negligible)
    if (t < NC) {
        float n = (float)cls_num[t];
        wsh[t] = OMB / (1.0f - powf(0.9999f, n));   // numerator cancels in normalization
    }
    __syncthreads();
    if (t == 0) {
        float s = 0.0f;
        for (int c = 0; c < NC; c++) s += wsh[c];
        wsum_sh = s;
    }
    __syncthreads();
    if (t < NC) wsh[t] = wsh[t] / wsum_sh;   // safe: wsh not read until after next barrier

    // ---------------- phase A: codes + regression + positive queue ----------------
    const float SL1B = 1.0f / 9.0f;
    float regsum = 0.0f;
    int pcnt = 0;
    int a0 = chunk * APC;
    for (int al = t; al < APC; al += 256) {
        int a = a0 + al;
        float4 cf = ((const float4*)anchors)[a];
        float ax1 = cf.x - cf.z * 0.5f, ay1 = cf.y - cf.w * 0.5f;
        float ax2 = cf.x + cf.z * 0.5f, ay2 = cf.y + cf.w * 0.5f;
        float aarea = (ax2 - ax1) * (ay2 - ay1);
        float best = -1.0f; int bm = 0;
        for (int m = 0; m < cnt; m++) {
            float ltx = fmaxf(sg[m][0], ax1), lty = fmaxf(sg[m][1], ay1);
            float rbx = fminf(sg[m][2], ax2), rby = fminf(sg[m][3], ay2);
            float wx = fmaxf(rbx - ltx, 0.0f), wy = fmaxf(rby - lty, 0.0f);
            float inter = wx * wy;
            float iou = inter / (sg[m][4] + aarea - inter + 1e-10f);
            if (iou > best) { best = iou; bm = m; }   // strict >: first m wins ties
        }
        for (int m = 0; m < cnt; m++) {               // ascending: last match wins
            if (abest[m] == (unsigned)a) { best = 2.0f; bm = m; }
        }
        int code;
        if (cnt == 0) code = -1;
        else if (best < NEG_TH) code = 0;
        else if (best < POS_TH) code = -1;
        else code = bm + 1;
        maskG[(size_t)bs * NA + a] = (code == -1) ? 0.0f : 1.0f;
        if (code > 0) {
            pcnt++;
            size_t ia = (size_t)bs * NA + a;
            float mx1 = sg[bm][0], my1 = sg[bm][1], mx2 = sg[bm][2], my2 = sg[bm][3];
            float g0 = ((mx1 + mx2) * 0.5f - cf.x) / (0.1f * cf.z);
            float g1 = ((my1 + my2) * 0.5f - cf.y) / (0.1f * cf.w);
            float g2 = logf(fmaxf(mx2 - mx1, 1e-6f) / cf.z) / 0.2f;
            float g3 = logf(fmaxf(my2 - my1, 1e-6f) / cf.w) / 0.2f;
            float4 p = ((const float4*)ploc)[ia];
            float n0 = fabsf(p.x - g0), n1 = fabsf(p.y - g1);
            float n2 = fabsf(p.z - g2), n3 = fabsf(p.w - g3);
            float s0 = n0 < SL1B ? 0.5f * n0 * n0 / SL1B : n0 - 0.5f * SL1B;
            float s1 = n1 < SL1B ? 0.5f * n1 * n1 / SL1B : n1 - 0.5f * SL1B;
            float s2 = n2 < SL1B ? 0.5f * n2 * n2 / SL1B : n2 - 0.5f * SL1B;
            float s3 = n3 < SL1B ? 0.5f * n3 * n3 / SL1B : n3 - 0.5f * SL1B;
            regsum += s0 + s1 + s2 + s3;
            int q = atomicAdd(&npq, 1);
            qpos[q] = ((unsigned)bm << 16) | (unsigned)al;
        }
    }
    __syncthreads();

    // ---------------- phase B: cooperative positive-class corrections ------------------
    // Items = nPos x 20 quads; lanes read one row's 320B contiguously (coalesced),
    // all lanes active. corr = w*ls*(e*p) - OMB*(x+ls)*p per y==1 element.
    float corrsum = 0.0f;
    int nq = npq;
    for (int i = t; i < nq * 20; i += 256) {
        int qq = i / 20, c4 = i % 20;
        unsigned e = qpos[qq];
        int al = e & 0xFFFFu;
        int m  = (int)(e >> 16);
        float4 y4 = ((const float4*)(gtl + ((size_t)(bs * NM + m)) * NC))[c4];
        if (y4.x > 0.5f || y4.y > 0.5f || y4.z > 0.5f || y4.w > 0.5f) {
            float4 x4 = ((const float4*)(logits + ((size_t)bs * NA + a0 + al) * NC))[c4];
            float yv[4] = {y4.x, y4.y, y4.z, y4.w};
            float xv[4] = {x4.x, x4.y, x4.z, x4.w};
            #pragma unroll
            for (int j = 0; j < 4; j++) {
                if (yv[j] > 0.5f) {
                    float x = xv[j];
                    float ee = __expf(-x);
                    float s = 1.0f + ee;
                    float pr = __builtin_amdgcn_rcpf(s);
                    float ls = __logf(s);
                    corrsum += ls * wsh[c4 * 4 + j] * (ee * pr)
                             - OMB * (x + ls) * pr;
                }
            }
        }
    }

    // wave shfl-reduce then cross-wave LDS then one atomic per block
    #pragma unroll
    for (int off = 32; off > 0; off >>= 1) {
        regsum  += __shfl_xor(regsum, off);
        corrsum += __shfl_xor(corrsum, off);
        pcnt    += __shfl_xor(pcnt, off);
    }
    __shared__ float sf[4], sc[4];
    __shared__ int   si[4];
    int wave = t >> 6, lane = t & 63;
    if (lane == 0) { sf[wave] = regsum; sc[wave] = corrsum; si[wave] = pcnt; }
    __syncthreads();
    if (t == 0) {
        atomicAdd(&acc[0], (double)(sf[0] + sf[1] + sf[2] + sf[3]));
        atomicAdd(&acc[1], (double)(sc[0] + sc[1] + sc[2] + sc[3]));
        atomicAdd(npos, si[0] + si[1] + si[2] + si[3]);
    }
}

// ---------------- kernel 3: dense background stream, max outstanding loads ------------
// 3000 blocks x 256 threads x 10 float4. ALL 20 loads (10 mask dwords + 10 logits
// float4, NT) issue before any consumption; NO LDS/barrier until the final reduce, so
// nothing drains vmcnt. Mask is a 1.5MB float array (L2/L3-hot, ~4 distinct dwords
// per wave-instruction). Identity: term = (x + log(1+e^-x)) * sigmoid(x).
__global__ void __launch_bounds__(256, 4)
k_cls(const float* __restrict__ logits, const float* __restrict__ maskG,
      double* __restrict__ acc) {
    int t = threadIdx.x;
    unsigned f40 = (unsigned)blockIdx.x * CLS_F4_PER_BLOCK + (unsigned)t;
    const float4* x4p = (const float4*)logits;

    float4 xs[10];
    float  ms[10];
    #pragma unroll
    for (int k = 0; k < 10; k++) {
        unsigned i = f40 + (unsigned)(k * 256);
        ms[k] = maskG[i / 20u];        // cached load, const-divisor magic mul
        xs[k] = ntload4(&x4p[i]);      // NT: no allocation, no dirty-victim writeback
    }
    float bgsum = 0.0f;
    #pragma unroll
    for (int k = 0; k < 10; k++) {
        float xv[4] = {xs[k].x, xs[k].y, xs[k].z, xs[k].w};
        float tsum = 0.0f;
        #pragma unroll
        for (int jj = 0; jj < 4; jj++) {
            float x = xv[jj];
            float e = __expf(-x);
            float s = 1.0f + e;
            float pr = __builtin_amdgcn_rcpf(s);
            float ls = __logf(s);
            tsum += (x + ls) * pr;
        }
        bgsum = fmaf(ms[k], tsum, bgsum);
    }

    #pragma unroll
    for (int off = 32; off > 0; off >>= 1) bgsum += __shfl_xor(bgsum, off);
    __shared__ float sb[4];
    int wave = t >> 6, lane = t & 63;
    if (lane == 0) sb[wave] = bgsum;
    __syncthreads();
    if (t == 0) atomicAdd(&acc[1], (double)(OMB * (sb[0] + sb[1] + sb[2] + sb[3])));
}

// ---------------- kernel 4: ego focal loss + final combine ----------------
__global__ void k_final(const float* __restrict__ ego_preds, const int* __restrict__ ego_labels,
                        const double* __restrict__ acc, const int* __restrict__ npos,
                        float* __restrict__ out) {
    __shared__ float scol[NCE];
    __shared__ float sred[128];
    __shared__ int   sval[128];
    const float EPSF = 1e-7f;
    int t = threadIdx.x;
    if (t < NCE) {
        float c = 0.0f;
        for (int i = 0; i < NBS; i++) {
            int l = ego_labels[i];
            if (l > -1 && l == t) c = 1.0f;
        }
        scol[t] = c;
    }
    __syncthreads();

    float term = 0.0f;
    if (t < NBS * NCE) {
        int bs = t / NCE, e = t % NCE;
        int lbl = ego_labels[bs];
        if (lbl > -1) {
            float x = ego_preds[t];
            float ep = 1.0f / (1.0f + expf(-x));
            float oh = scol[e];
            float af = 0.25f * oh + 0.75f * (1.0f - oh);
            float ept = ep * oh + (1.0f - ep) * (1.0f - oh);
            float epc = fminf(fmaxf(ep, EPSF), 1.0f - EPSF);
            float bce = -(oh * logf(epc) + (1.0f - oh) * log1pf(-epc));
            float om = 1.0f - ept;
            term = bce * af * om * om;
        }
    }
    sred[t] = term;
    sval[t] = (t < NBS && ego_labels[t] > -1) ? 1 : 0;
    __syncthreads();
    for (int off = 64; off > 0; off >>= 1) {
        if (t < off) { sred[t] += sred[t + off]; sval[t] += sval[t + off]; }
        __syncthreads();
    }
    if (t == 0) {
        float esum = sred[0];
        int ne = sval[0];
        float ego = (ne > 0) ? esum / (float)(ne > 1 ? ne : 1) : 0.0f;
        double npd = (double)(*npos);
        if (npd < 1.0) npd = 1.0;
        out[0] = (float)(acc[0] / (npd * 4.0));
        out[1] = (float)(acc[1] / npd / 8.0 + (double)ego / 4.0);
    }
}

// ---------------- host launch ----------------
extern "C" void kernel_launch(void* const* d_in, const int* in_sizes, int n_in,
                              void* d_out, int out_size, void* d_ws, size_t ws_size,
                              hipStream_t stream) {
    const float* confidence = (const float*)d_in[0];
    const float* ploc       = (const float*)d_in[1];
    const float* gtb        = (const float*)d_in[2];
    const float* gtl        = (const float*)d_in[3];
    const int*   counts     = (const int*)d_in[4];
    const float* anchors    = (const float*)d_in[5];
    const float* ego_preds  = (const float*)d_in[6];
    const int*   ego_labels = (const int*)d_in[7];
    const int*   cls_num    = (const int*)d_in[8];
    float* out = (float*)d_out;

    // workspace layout: [acc 2xf64 | npos | pad | gbest 320xu64 | pad | maskG 384000xf32]
    char* ws = (char*)d_ws;
    double* acc  = (double*)ws;                               // [0]=reg_sum, [1]=cls_sum
    int* npos    = (int*)(ws + 16);
    unsigned long long* gbest = (unsigned long long*)(ws + 64);   // 320 u64 = 2560 B
    float* maskG = (float*)(ws + 4096);                       // 16*24000 f32 = 1.536 MB

    hipMemsetAsync(ws, 0, 4096, stream);   // graph memset node: acc, npos, gbest -> 0
    k_gbest<<<NBS * CPB, 256, 0, stream>>>(gtb, counts, anchors, gbest);
    k_match<<<NBS * CPB, 256, 0, stream>>>(gtb, counts, anchors, ploc, gtl, confidence,
                                           cls_num, gbest, maskG, acc, npos);
    k_cls<<<CLS_BLOCKS, 256, 0, stream>>>(confidence, maskG, acc);
    k_final<<<1, 128, 0, stream>>>(ego_preds, ego_labels, acc, npos, out);
}

// Round 5
// 261.500 us; speedup vs baseline: 1.0579x; 1.0579x over previous
//
#include <hip/hip_runtime.h>
#include <math.h>

// Problem constants (match reference)
#define NB 2
#define NS 8
#define NA 24000
#define NC 80
#define NM 20
#define NCE 7
#define NBS (NB*NS)          // 16 frames
#define CPB 75               // chunks per frame
#define APC (NA/CPB)         // anchors per chunk = 320

#define POS_TH 0.5f
#define NEG_TH 0.4f
#define OMB 1e-4f            // 1.0 - 0.9999 (correctly rounded to f32)
#define SL1B (1.0f/9.0f)

// pack (iou, anchor_idx) into u64 so that max-reduce picks higher iou,
// tie -> smaller anchor index (argmax first-occurrence semantics)
__device__ inline unsigned long long packKey(float f, unsigned idx) {
    unsigned u = __float_as_uint(f);
    u = (u & 0x80000000u) ? ~u : (u | 0x80000000u);   // total order on floats
    return ((unsigned long long)u << 32) | (unsigned long long)(0xFFFFFFFFu - idx);
}

// ================= mega kernel: 3 independent roles co-scheduled ======================
// role 0 (stream): maskless TOTAL background sum over this unit's contiguous logits
//                  slab (empty frames skipped: their mask is all-zero => net 0).
// role 1 (match):  provisional (NO force-match) codes, regression, positive y==1
//                  corrections, and subtraction of ignored (code==-1) rows from the
//                  total. Force-match is applied later as tiny deltas in k_final.
// role 2 (gbest):  per-gt global best anchor via u64 atomicMax.
// All three are mutually independent -> single launch, scheduler overlaps the
// latency-bound stream with the VALU-bound match/gbest blocks.
// Identities (e=exp(-x), s=1+e, p=1/s): -log(p)=log(s), -log(1-p)=x+log(s), 1-p=e*p.
__global__ void __launch_bounds__(256)
k_mega(const float* __restrict__ gtb, const int* __restrict__ counts,
       const float* __restrict__ anchors, const float* __restrict__ ploc,
       const float* __restrict__ gtl, const float* __restrict__ logits,
       const int* __restrict__ cls_num, unsigned long long* __restrict__ gbest,
       double* __restrict__ acc, int* __restrict__ npos) {
    __shared__ float sg[NM][5];               // gt x1,y1,x2,y2,area
    __shared__ unsigned long long sk[4][NM];  // role2 cross-wave reduce
    __shared__ double sb[4];                  // role0 cross-wave reduce
    __shared__ float wsh[NC];
    __shared__ float wsum_sh;
    __shared__ unsigned qpos[APC];            // (gt_idx<<16) | local_anchor
    __shared__ unsigned qign[APC];            // local_anchor
    __shared__ int npq, nqi;
    __shared__ float sf[4], sc[4];
    __shared__ int si[4];

    int bid = blockIdx.x;
    int role = bid % 3;                       // interleave roles across CUs/XCDs
    int u = bid / 3;                          // 0..1199
    int bs = u / CPB, chunk = u % CPB;
    int t = threadIdx.x;
    int cnt = counts[bs];
    int a0 = chunk * APC;
    int wave = t >> 6, lane = t & 63;

    if (cnt == 0) return;                     // block-uniform for every role:
    // role0: all-ignored frame contributes net 0; role1: no codes/sums; role2: no gts.

    if (role == 0) {
        // ---------------- dense background stream over 100KB slab ----------------
        const float4* x4p = (const float4*)logits + ((size_t)bs * NA + a0) * (NC / 4);
        double bg = 0.0;
        #pragma unroll
        for (int g = 0; g < 5; g++) {
            float4 xs[5];
            #pragma unroll
            for (int j = 0; j < 5; j++) xs[j] = x4p[t + (g * 5 + j) * 256];
            #pragma unroll
            for (int j = 0; j < 5; j++) {
                float xv[4] = {xs[j].x, xs[j].y, xs[j].z, xs[j].w};
                float tsum = 0.0f;
                #pragma unroll
                for (int jj = 0; jj < 4; jj++) {
                    float x = xv[jj];
                    float e = __expf(-x);
                    float s = 1.0f + e;
                    float pr = __builtin_amdgcn_rcpf(s);
                    float ls = __logf(s);
                    tsum += (x + ls) * pr;
                }
                bg += (double)tsum;
            }
        }
        #pragma unroll
        for (int off = 32; off > 0; off >>= 1) bg += __shfl_xor(bg, off);
        if (lane == 0) sb[wave] = bg;
        __syncthreads();
        if (t == 0) atomicAdd(&acc[1], (double)OMB * (sb[0] + sb[1] + sb[2] + sb[3]));
        return;
    }

    if (role == 2) {
        // ---------------- per-gt global best anchor ----------------
        if (t < NM) {
            const float* g = gtb + ((size_t)bs * NM + t) * 4;
            float x1 = g[0], y1 = g[1], x2 = g[2], y2 = g[3];
            sg[t][0] = x1; sg[t][1] = y1; sg[t][2] = x2; sg[t][3] = y2;
            sg[t][4] = (x2 - x1) * (y2 - y1);
        }
        __syncthreads();
        bool has2 = t < (APC - 256);
        float4 c1 = ((const float4*)anchors)[a0 + t];
        float bx1 = c1.x - c1.z * 0.5f, by1 = c1.y - c1.w * 0.5f;
        float bx2 = c1.x + c1.z * 0.5f, by2 = c1.y + c1.w * 0.5f;
        float bar = (bx2 - bx1) * (by2 - by1);
        float cx1 = 0, cy1 = 0, cx2 = 0, cy2 = 0, car = 0;
        if (has2) {
            float4 c2 = ((const float4*)anchors)[a0 + 256 + t];
            cx1 = c2.x - c2.z * 0.5f; cy1 = c2.y - c2.w * 0.5f;
            cx2 = c2.x + c2.z * 0.5f; cy2 = c2.y + c2.w * 0.5f;
            car = (cx2 - cx1) * (cy2 - cy1);
        }
        for (int m = 0; m < cnt; m++) {
            float gx1 = sg[m][0], gy1 = sg[m][1], gx2 = sg[m][2], gy2 = sg[m][3], gar = sg[m][4];
            float ltx = fmaxf(gx1, bx1), lty = fmaxf(gy1, by1);
            float rbx = fminf(gx2, bx2), rby = fminf(gy2, by2);
            float wx = fmaxf(rbx - ltx, 0.0f), wy = fmaxf(rby - lty, 0.0f);
            float inter = wx * wy;
            float iou = inter / (gar + bar - inter + 1e-10f);  // IEEE div: threshold-exact
            unsigned long long k = packKey(iou, (unsigned)(a0 + t));
            if (has2) {
                float ltx2 = fmaxf(gx1, cx1), lty2 = fmaxf(gy1, cy1);
                float rbx2 = fminf(gx2, cx2), rby2 = fminf(gy2, cy2);
                float wx2 = fmaxf(rbx2 - ltx2, 0.0f), wy2 = fmaxf(rby2 - lty2, 0.0f);
                float inter2 = wx2 * wy2;
                float iou2 = inter2 / (gar + car - inter2 + 1e-10f);
                unsigned long long k2 = packKey(iou2, (unsigned)(a0 + 256 + t));
                if (k2 > k) k = k2;
            }
            #pragma unroll
            for (int off = 32; off > 0; off >>= 1) {
                unsigned long long o = __shfl_xor(k, off);
                if (o > k) k = o;
            }
            if (lane == 0) sk[wave][m] = k;
        }
        __syncthreads();
        if (t < cnt) {
            unsigned long long k = sk[0][t];
            if (sk[1][t] > k) k = sk[1][t];
            if (sk[2][t] > k) k = sk[2][t];
            if (sk[3][t] > k) k = sk[3][t];
            atomicMax(&gbest[bs * NM + t], k);
        }
        return;
    }

    // ---------------- role 1: provisional match + regression + corrections ----------
    if (t == 0) { npq = 0; nqi = 0; }
    if (t < NM) {
        const float* g = gtb + ((size_t)bs * NM + t) * 4;
        float x1 = g[0], y1 = g[1], x2 = g[2], y2 = g[3];
        sg[t][0] = x1; sg[t][1] = y1; sg[t][2] = x2; sg[t][3] = y2;
        sg[t][4] = (x2 - x1) * (y2 - y1);
    }
    if (t < NC) {
        float n = (float)cls_num[t];
        wsh[t] = OMB / (1.0f - powf(0.9999f, n));   // numerator cancels in normalization
    }
    __syncthreads();
    if (t == 0) {
        float s = 0.0f;
        for (int c = 0; c < NC; c++) s += wsh[c];
        wsum_sh = s;
    }
    __syncthreads();
    if (t < NC) wsh[t] = wsh[t] / wsum_sh;   // read only after the phase-A barrier

    float regsum = 0.0f;
    int pcnt = 0;
    for (int al = t; al < APC; al += 256) {
        int a = a0 + al;
        float4 cf = ((const float4*)anchors)[a];
        float ax1 = cf.x - cf.z * 0.5f, ay1 = cf.y - cf.w * 0.5f;
        float ax2 = cf.x + cf.z * 0.5f, ay2 = cf.y + cf.w * 0.5f;
        float aarea = (ax2 - ax1) * (ay2 - ay1);
        float best = -1.0f; int bm = 0;
        for (int m = 0; m < cnt; m++) {
            float ltx = fmaxf(sg[m][0], ax1), lty = fmaxf(sg[m][1], ay1);
            float rbx = fminf(sg[m][2], ax2), rby = fminf(sg[m][3], ay2);
            float wx = fmaxf(rbx - ltx, 0.0f), wy = fmaxf(rby - lty, 0.0f);
            float inter = wx * wy;
            float iou = inter / (sg[m][4] + aarea - inter + 1e-10f);
            if (iou > best) { best = iou; bm = m; }   // strict >: first m wins ties
        }
        // NO force-match here: applied as deltas in k_final (<=320 anchors).
        int code = (best < NEG_TH) ? 0 : (best < POS_TH) ? -1 : bm + 1;
        if (code > 0) {
            pcnt++;
            size_t ia = (size_t)bs * NA + a;
            float mx1 = sg[bm][0], my1 = sg[bm][1], mx2 = sg[bm][2], my2 = sg[bm][3];
            float g0 = ((mx1 + mx2) * 0.5f - cf.x) / (0.1f * cf.z);
            float g1 = ((my1 + my2) * 0.5f - cf.y) / (0.1f * cf.w);
            float g2 = logf(fmaxf(mx2 - mx1, 1e-6f) / cf.z) / 0.2f;
            float g3 = logf(fmaxf(my2 - my1, 1e-6f) / cf.w) / 0.2f;
            float4 p = ((const float4*)ploc)[ia];
            float n0 = fabsf(p.x - g0), n1 = fabsf(p.y - g1);
            float n2 = fabsf(p.z - g2), n3 = fabsf(p.w - g3);
            float s0 = n0 < SL1B ? 0.5f * n0 * n0 / SL1B : n0 - 0.5f * SL1B;
            float s1 = n1 < SL1B ? 0.5f * n1 * n1 / SL1B : n1 - 0.5f * SL1B;
            float s2 = n2 < SL1B ? 0.5f * n2 * n2 / SL1B : n2 - 0.5f * SL1B;
            float s3 = n3 < SL1B ? 0.5f * n3 * n3 / SL1B : n3 - 0.5f * SL1B;
            regsum += s0 + s1 + s2 + s3;
            int q = atomicAdd(&npq, 1);
            qpos[q] = ((unsigned)bm << 16) | (unsigned)al;
        } else if (code == -1) {
            int q = atomicAdd(&nqi, 1);
            qign[q] = (unsigned)al;
        }
    }
    __syncthreads();

    // positive y==1 corrections (cooperative, coalesced 320B rows)
    float corrsum = 0.0f;
    int nq = npq, ni = nqi;
    for (int i = t; i < nq * 20; i += 256) {
        int qq = i / 20, c4 = i % 20;
        unsigned e = qpos[qq];
        int al = e & 0xFFFFu;
        int m  = (int)(e >> 16);
        float4 y4 = ((const float4*)(gtl + ((size_t)(bs * NM + m)) * NC))[c4];
        if (y4.x > 0.5f || y4.y > 0.5f || y4.z > 0.5f || y4.w > 0.5f) {
            float4 x4 = ((const float4*)logits)[((size_t)bs * NA + a0 + al) * (NC / 4) + c4];
            float yv[4] = {y4.x, y4.y, y4.z, y4.w};
            float xv[4] = {x4.x, x4.y, x4.z, x4.w};
            #pragma unroll
            for (int j = 0; j < 4; j++) {
                if (yv[j] > 0.5f) {
                    float x = xv[j];
                    float ee = __expf(-x);
                    float s = 1.0f + ee;
                    float pr = __builtin_amdgcn_rcpf(s);
                    float ls = __logf(s);
                    corrsum += ls * wsh[c4 * 4 + j] * (ee * pr)
                             - OMB * (x + ls) * pr;
                }
            }
        }
    }
    // ignored rows: subtract from the maskless total (cooperative, coalesced)
    float negsum = 0.0f;
    for (int i = t; i < ni * 20; i += 256) {
        int qq = i / 20, c4 = i % 20;
        int al = (int)qign[qq];
        float4 x4 = ((const float4*)logits)[((size_t)bs * NA + a0 + al) * (NC / 4) + c4];
        float xv[4] = {x4.x, x4.y, x4.z, x4.w};
        float rs = 0.0f;
        #pragma unroll
        for (int j = 0; j < 4; j++) {
            float x = xv[j];
            float e = __expf(-x);
            float s = 1.0f + e;
            float pr = __builtin_amdgcn_rcpf(s);
            float ls = __logf(s);
            rs += (x + ls) * pr;
        }
        negsum += rs;
    }
    float clssum = corrsum - OMB * negsum;

    #pragma unroll
    for (int off = 32; off > 0; off >>= 1) {
        regsum += __shfl_xor(regsum, off);
        clssum += __shfl_xor(clssum, off);
        pcnt   += __shfl_xor(pcnt, off);
    }
    if (lane == 0) { sf[wave] = regsum; sc[wave] = clssum; si[wave] = pcnt; }
    __syncthreads();
    if (t == 0) {
        atomicAdd(&acc[0], (double)(sf[0] + sf[1] + sf[2] + sf[3]));
        atomicAdd(&acc[1], (double)(sc[0] + sc[1] + sc[2] + sc[3]));
        atomicAdd(npos, si[0] + si[1] + si[2] + si[3]);
    }
}

// ================= k_final: force-match fixup (<=320 anchors) + ego + combine =========
__global__ void __launch_bounds__(256)
k_final(const float* __restrict__ gtb, const int* __restrict__ counts,
        const float* __restrict__ anchors, const float* __restrict__ ploc,
        const float* __restrict__ gtl, const float* __restrict__ logits,
        const int* __restrict__ cls_num, const unsigned long long* __restrict__ gbest,
        const float* __restrict__ ego_preds, const int* __restrict__ ego_labels,
        const double* __restrict__ acc, const int* __restrict__ npos,
        float* __restrict__ out) {
    __shared__ float sg[NBS][NM][5];
    __shared__ unsigned sA[NBS][NM];
    __shared__ int scnt[NBS];
    __shared__ float wsh[NC];
    __shared__ float wsum_sh;
    __shared__ float scol[NCE];
    __shared__ float sdr[256], sdc[256];
    __shared__ int sdn[256];
    __shared__ float sred[256];
    __shared__ int sval[256];
    const float EPSF = 1e-7f;
    int t = threadIdx.x;

    if (t < NBS) scnt[t] = counts[t];
    if (t < NC) {
        float n = (float)cls_num[t];
        wsh[t] = OMB / (1.0f - powf(0.9999f, n));
    }
    if (t < NCE) {
        float c = 0.0f;
        for (int i = 0; i < NBS; i++) {
            int l = ego_labels[i];
            if (l > -1 && l == t) c = 1.0f;
        }
        scol[t] = c;
    }
    __syncthreads();
    if (t < NBS * NM) {
        int bs = t / NM, m = t % NM;
        const float* g = gtb + (size_t)t * 4;
        float x1 = g[0], y1 = g[1], x2 = g[2], y2 = g[3];
        sg[bs][m][0] = x1; sg[bs][m][1] = y1; sg[bs][m][2] = x2; sg[bs][m][3] = y2;
        sg[bs][m][4] = (x2 - x1) * (y2 - y1);
        sA[bs][m] = (m < scnt[bs])
            ? (unsigned)(0xFFFFFFFFu - (unsigned)(gbest[t] & 0xFFFFFFFFull))
            : 0xFFFFFFFFu;
    }
    if (t == 0) {
        float s = 0.0f;
        for (int c = 0; c < NC; c++) s += wsh[c];
        wsum_sh = s;
    }
    __syncthreads();
    if (t < NC) wsh[t] = wsh[t] / wsum_sh;
    __syncthreads();

    // ---- force-match deltas: thread per (bs, m) ----
    float dreg = 0.0f, dcls = 0.0f; int dnp = 0;
    if (t < NBS * NM) {
        int bs = t / NM, m = t % NM;
        int cnt = scnt[bs];
        if (m < cnt) {
            unsigned a = sA[bs][m];
            bool overridden = false;                       // later gt claiming same anchor wins
            for (int m2 = m + 1; m2 < cnt; m2++)
                if (sA[bs][m2] == a) overridden = true;
            if (!overridden) {
                float4 cf = ((const float4*)anchors)[a];
                float ax1 = cf.x - cf.z * 0.5f, ay1 = cf.y - cf.w * 0.5f;
                float ax2 = cf.x + cf.z * 0.5f, ay2 = cf.y + cf.w * 0.5f;
                float aarea = (ax2 - ax1) * (ay2 - ay1);
                float best = -1.0f; int bm = 0;
                for (int m2 = 0; m2 < cnt; m2++) {
                    float ltx = fmaxf(sg[bs][m2][0], ax1), lty = fmaxf(sg[bs][m2][1], ay1);
                    float rbx = fminf(sg[bs][m2][2], ax2), rby = fminf(sg[bs][m2][3], ay2);
                    float wx = fmaxf(rbx - ltx, 0.0f), wy = fmaxf(rby - lty, 0.0f);
                    float inter = wx * wy;
                    float iou = inter / (sg[bs][m2][4] + aarea - inter + 1e-10f);
                    if (iou > best) { best = iou; bm = m2; }
                }
                int code = (best < NEG_TH) ? 0 : (best < POS_TH) ? -1 : bm + 1;
                if (!(code > 0 && bm == m)) {             // identical match -> no-op
                    size_t ia = (size_t)bs * NA + a;
                    float4 p = ((const float4*)ploc)[ia];
                    auto sl1 = [&](int mm) -> float {      // bit-identical to role1's formula
                        float mx1 = sg[bs][mm][0], my1 = sg[bs][mm][1];
                        float mx2 = sg[bs][mm][2], my2 = sg[bs][mm][3];
                        float g0 = ((mx1 + mx2) * 0.5f - cf.x) / (0.1f * cf.z);
                        float g1 = ((my1 + my2) * 0.5f - cf.y) / (0.1f * cf.w);
                        float g2 = logf(fmaxf(mx2 - mx1, 1e-6f) / cf.z) / 0.2f;
                        float g3 = logf(fmaxf(my2 - my1, 1e-6f) / cf.w) / 0.2f;
                        float n0 = fabsf(p.x - g0), n1 = fabsf(p.y - g1);
                        float n2 = fabsf(p.z - g2), n3 = fabsf(p.w - g3);
                        float s0 = n0 < SL1B ? 0.5f * n0 * n0 / SL1B : n0 - 0.5f * SL1B;
                        float s1 = n1 < SL1B ? 0.5f * n1 * n1 / SL1B : n1 - 0.5f * SL1B;
                        float s2 = n2 < SL1B ? 0.5f * n2 * n2 / SL1B : n2 - 0.5f * SL1B;
                        float s3 = n3 < SL1B ? 0.5f * n3 * n3 / SL1B : n3 - 0.5f * SL1B;
                        return s0 + s1 + s2 + s3;
                    };
                    dreg += sl1(m);                        // new positive (idx m)
                    if (code > 0) dreg -= sl1(bm);         // was positive with other gt
                    else dnp += 1;                         // background/ignored -> positive
                    const float* xrow = logits + ia * NC;
                    const float* ynew = gtl + ((size_t)(bs * NM + m)) * NC;
                    const float* yold = gtl + ((size_t)(bs * NM + bm)) * NC;
                    bool addbg = (code == -1);             // row was subtracted by role1
                    for (int c = 0; c < NC; c++) {
                        float x = xrow[c];
                        float e = __expf(-x);
                        float s = 1.0f + e;
                        float pr = __builtin_amdgcn_rcpf(s);
                        float ls = __logf(s);
                        float bgterm = OMB * (x + ls) * pr;
                        if (addbg) dcls += bgterm;         // re-add row to background total
                        if (ynew[c] > 0.5f)
                            dcls += ls * wsh[c] * (e * pr) - bgterm;
                        if (code > 0 && yold[c] > 0.5f)
                            dcls -= ls * wsh[c] * (e * pr) - bgterm;
                    }
                }
            }
        }
    }
    sdr[t] = dreg; sdc[t] = dcls; sdn[t] = dnp;

    // ---- ego focal loss ----
    float term = 0.0f;
    if (t < NBS * NCE) {
        int bs = t / NCE, e = t % NCE;
        int lbl = ego_labels[bs];
        if (lbl > -1) {
            float x = ego_preds[t];
            float ep = 1.0f / (1.0f + expf(-x));
            float oh = scol[e];
            float af = 0.25f * oh + 0.75f * (1.0f - oh);
            float ept = ep * oh + (1.0f - ep) * (1.0f - oh);
            float epc = fminf(fmaxf(ep, EPSF), 1.0f - EPSF);
            float bce = -(oh * logf(epc) + (1.0f - oh) * log1pf(-epc));
            float om = 1.0f - ept;
            term = bce * af * om * om;
        }
    }
    sred[t] = term;
    sval[t] = (t < NBS && ego_labels[t] > -1) ? 1 : 0;
    __syncthreads();
    for (int off = 128; off > 0; off >>= 1) {
        if (t < off) {
            sdr[t] += sdr[t + off]; sdc[t] += sdc[t + off]; sdn[t] += sdn[t + off];
            sred[t] += sred[t + off]; sval[t] += sval[t + off];
        }
        __syncthreads();
    }
    if (t == 0) {
        float esum = sred[0];
        int ne = sval[0];
        float ego = (ne > 0) ? esum / (float)(ne > 1 ? ne : 1) : 0.0f;
        double npd = (double)(*npos + sdn[0]);
        if (npd < 1.0) npd = 1.0;
        double regT = acc[0] + (double)sdr[0];
        double clsT = acc[1] + (double)sdc[0];
        out[0] = (float)(regT / (npd * 4.0));
        out[1] = (float)(clsT / npd / 8.0 + (double)ego / 4.0);
    }
}

// ---------------- host launch ----------------
extern "C" void kernel_launch(void* const* d_in, const int* in_sizes, int n_in,
                              void* d_out, int out_size, void* d_ws, size_t ws_size,
                              hipStream_t stream) {
    const float* confidence = (const float*)d_in[0];
    const float* ploc       = (const float*)d_in[1];
    const float* gtb        = (const float*)d_in[2];
    const float* gtl        = (const float*)d_in[3];
    const int*   counts     = (const int*)d_in[4];
    const float* anchors    = (const float*)d_in[5];
    const float* ego_preds  = (const float*)d_in[6];
    const int*   ego_labels = (const int*)d_in[7];
    const int*   cls_num    = (const int*)d_in[8];
    float* out = (float*)d_out;

    // workspace: [acc 2xf64 | npos | pad | gbest 320xu64]
    char* ws = (char*)d_ws;
    double* acc  = (double*)ws;                               // [0]=reg_sum, [1]=cls_sum
    int* npos    = (int*)(ws + 16);
    unsigned long long* gbest = (unsigned long long*)(ws + 64);   // 320 u64 = 2560 B

    hipMemsetAsync(ws, 0, 4096, stream);      // zero acc, npos, gbest
    k_mega<<<3 * NBS * CPB, 256, 0, stream>>>(gtb, counts, anchors, ploc, gtl,
                                              confidence, cls_num, gbest, acc, npos);
    k_final<<<1, 256, 0, stream>>>(gtb, counts, anchors, ploc, gtl, confidence,
                                   cls_num, gbest, ego_preds, ego_labels,
                                   acc, npos, out);
}

// Round 7
// 244.617 us; speedup vs baseline: 1.1309x; 1.0690x over previous
//
#include <hip/hip_runtime.h>
#include <math.h>

// Problem constants (match reference)
#define NB 2
#define NS 8
#define NA 24000
#define NC 80
#define NM 20
#define NCE 7
#define NBS (NB*NS)          // 16 frames
#define CPB 75               // chunks per frame
#define APC (NA/CPB)         // anchors per chunk = 320
#define NUNITS (3*NBS*CPB)   // 3600 blocks: role = bid%3, unit = bid/3

#define POS_TH 0.5f
#define NEG_TH 0.4f
#define OMB 1e-4f            // 1.0 - 0.9999 (correctly rounded to f32)
#define SL1B (1.0f/9.0f)

// pack (iou, anchor_idx) into u64 so that max-reduce picks higher iou,
// tie -> smaller anchor index (argmax first-occurrence semantics)
__device__ inline unsigned long long packKey(float f, unsigned idx) {
    unsigned u = __float_as_uint(f);
    u = (u & 0x80000000u) ? ~u : (u | 0x80000000u);   // total order on floats
    return ((unsigned long long)u << 32) | (unsigned long long)(0xFFFFFFFFu - idx);
}

// ===================== kernel 1: 3 independent roles, no atomics, no init =============
// role 0: maskless TOTAL background sum over a contiguous 100KB logits slab,
//         ping-pong double-buffered loads (two 5xfloat4 batches in flight;
//         summation order bit-identical to the sequential version).
// role 1: provisional (no force-match) codes, regression, positive y==1 corrections,
//         subtraction of ignored rows from the total. Force-match deltas in k_final.
// role 2: per-(gt,chunk) best anchor -> chunkbest (plain writes; cnt==0 never read).
// Every block writes regp/clsp/npp[bid] unconditionally -> workspace needs NO init.
// Identities (e=exp(-x), s=1+e, p=1/s): -log(p)=log(s), -log(1-p)=x+log(s), 1-p=e*p.
__global__ void __launch_bounds__(256)
k_mega(const float* __restrict__ gtb, const int* __restrict__ counts,
       const float* __restrict__ anchors, const float* __restrict__ ploc,
       const float* __restrict__ gtl, const float* __restrict__ logits,
       const int* __restrict__ cls_num,
       unsigned long long* __restrict__ chunkbest,
       double* __restrict__ regp, double* __restrict__ clsp, int* __restrict__ npp) {
    __shared__ float sg[NM][5];               // gt x1,y1,x2,y2,area
    __shared__ unsigned long long sk[4][NM];  // role2 cross-wave reduce
    __shared__ double sb[4];                  // role0 cross-wave reduce
    __shared__ float wsh[NC];
    __shared__ float wsum_sh;
    __shared__ unsigned qpos[APC];            // (gt_idx<<16) | local_anchor
    __shared__ unsigned qign[APC];            // local_anchor
    __shared__ int npq, nqi;
    __shared__ float sf[4], sc[4];
    __shared__ int si[4];

    int bid = blockIdx.x;
    int role = bid % 3;                       // interleave roles across CUs/XCDs
    int unit = bid / 3;                       // 0..1199
    int bs = unit / CPB, chunk = unit % CPB;
    int t = threadIdx.x;
    int cnt = counts[bs];
    int a0 = chunk * APC;
    int wave = t >> 6, lane = t & 63;

    double accReg = 0.0, accCls = 0.0;        // thread 0's copies are the block result
    int accNp = 0;

    if (cnt != 0) {                           // empty frame: all contributions are 0
        if (role == 0) {
            // ---------- dense background stream, ping-pong double-buffer ----------
            const float4* x4p = (const float4*)logits + ((size_t)bs * NA + a0) * (NC / 4);
            float4 xa[5], xb[5];
            double bg = 0.0;
#define ISSUE(ARR,B) { _Pragma("unroll") \
            for (int j = 0; j < 5; j++) ARR[j] = x4p[t + ((B)*5 + j)*256]; }
#define CONSUME(ARR) { _Pragma("unroll") \
            for (int j = 0; j < 5; j++) { \
                float xv[4] = {ARR[j].x, ARR[j].y, ARR[j].z, ARR[j].w}; \
                float tsum = 0.0f; \
                _Pragma("unroll") \
                for (int jj = 0; jj < 4; jj++) { \
                    float x = xv[jj]; \
                    float e = __expf(-x); \
                    float s = 1.0f + e; \
                    float pr = __builtin_amdgcn_rcpf(s); \
                    float ls = __logf(s); \
                    tsum += (x + ls) * pr; \
                } \
                bg += (double)tsum; \
            } }
            ISSUE(xa, 0);
            ISSUE(xb, 1); CONSUME(xa);
            ISSUE(xa, 2); CONSUME(xb);
            ISSUE(xb, 3); CONSUME(xa);
            ISSUE(xa, 4); CONSUME(xb);
            CONSUME(xa);
#undef ISSUE
#undef CONSUME
            #pragma unroll
            for (int off = 32; off > 0; off >>= 1) bg += __shfl_xor(bg, off);
            if (lane == 0) sb[wave] = bg;
            __syncthreads();
            if (t == 0) accCls = (double)OMB * (sb[0] + sb[1] + sb[2] + sb[3]);
        } else if (role == 2) {
            // ---------- per-gt best anchor in this chunk -> chunkbest ----------
            if (t < NM) {
                const float* g = gtb + ((size_t)bs * NM + t) * 4;
                float x1 = g[0], y1 = g[1], x2 = g[2], y2 = g[3];
                sg[t][0] = x1; sg[t][1] = y1; sg[t][2] = x2; sg[t][3] = y2;
                sg[t][4] = (x2 - x1) * (y2 - y1);
            }
            __syncthreads();
            bool has2 = t < (APC - 256);
            float4 c1 = ((const float4*)anchors)[a0 + t];
            float bx1 = c1.x - c1.z * 0.5f, by1 = c1.y - c1.w * 0.5f;
            float bx2 = c1.x + c1.z * 0.5f, by2 = c1.y + c1.w * 0.5f;
            float bar = (bx2 - bx1) * (by2 - by1);
            float cx1 = 0, cy1 = 0, cx2 = 0, cy2 = 0, car = 0;
            if (has2) {
                float4 c2 = ((const float4*)anchors)[a0 + 256 + t];
                cx1 = c2.x - c2.z * 0.5f; cy1 = c2.y - c2.w * 0.5f;
                cx2 = c2.x + c2.z * 0.5f; cy2 = c2.y + c2.w * 0.5f;
                car = (cx2 - cx1) * (cy2 - cy1);
            }
            for (int m = 0; m < cnt; m++) {
                float gx1 = sg[m][0], gy1 = sg[m][1], gx2 = sg[m][2], gy2 = sg[m][3], gar = sg[m][4];
                float ltx = fmaxf(gx1, bx1), lty = fmaxf(gy1, by1);
                float rbx = fminf(gx2, bx2), rby = fminf(gy2, by2);
                float wx = fmaxf(rbx - ltx, 0.0f), wy = fmaxf(rby - lty, 0.0f);
                float inter = wx * wy;
                float iou = inter / (gar + bar - inter + 1e-10f);  // IEEE div: threshold-exact
                unsigned long long k = packKey(iou, (unsigned)(a0 + t));
                if (has2) {
                    float ltx2 = fmaxf(gx1, cx1), lty2 = fmaxf(gy1, cy1);
                    float rbx2 = fminf(gx2, cx2), rby2 = fminf(gy2, cy2);
                    float wx2 = fmaxf(rbx2 - ltx2, 0.0f), wy2 = fmaxf(rby2 - lty2, 0.0f);
                    float inter2 = wx2 * wy2;
                    float iou2 = inter2 / (gar + car - inter2 + 1e-10f);
                    unsigned long long k2 = packKey(iou2, (unsigned)(a0 + 256 + t));
                    if (k2 > k) k = k2;
                }
                #pragma unroll
                for (int off = 32; off > 0; off >>= 1) {
                    unsigned long long o = __shfl_xor(k, off);
                    if (o > k) k = o;
                }
                if (lane == 0) sk[wave][m] = k;
            }
            __syncthreads();
            if (t < NM) {
                unsigned long long k = 0ULL;
                if (t < cnt) {
                    k = sk[0][t];
                    if (sk[1][t] > k) k = sk[1][t];
                    if (sk[2][t] > k) k = sk[2][t];
                    if (sk[3][t] > k) k = sk[3][t];
                }
                chunkbest[(size_t)unit * NM + t] = k;   // write all NM (ws is poisoned)
            }
        } else {
            // ---------- role 1: provisional match + regression + corrections ----------
            if (t == 0) { npq = 0; nqi = 0; }
            if (t < NM) {
                const float* g = gtb + ((size_t)bs * NM + t) * 4;
                float x1 = g[0], y1 = g[1], x2 = g[2], y2 = g[3];
                sg[t][0] = x1; sg[t][1] = y1; sg[t][2] = x2; sg[t][3] = y2;
                sg[t][4] = (x2 - x1) * (y2 - y1);
            }
            if (t < NC) {
                float n = (float)cls_num[t];
                wsh[t] = OMB / (1.0f - powf(0.9999f, n));   // numerator cancels in normalization
            }
            __syncthreads();
            if (t == 0) {
                float s = 0.0f;
                for (int c = 0; c < NC; c++) s += wsh[c];
                wsum_sh = s;
            }
            __syncthreads();
            if (t < NC) wsh[t] = wsh[t] / wsum_sh;   // read only after the phase-A barrier

            float regsum = 0.0f;
            int pcnt = 0;
            for (int al = t; al < APC; al += 256) {
                int a = a0 + al;
                float4 cf = ((const float4*)anchors)[a];
                float ax1 = cf.x - cf.z * 0.5f, ay1 = cf.y - cf.w * 0.5f;
                float ax2 = cf.x + cf.z * 0.5f, ay2 = cf.y + cf.w * 0.5f;
                float aarea = (ax2 - ax1) * (ay2 - ay1);
                float best = -1.0f; int bm = 0;
                for (int m = 0; m < cnt; m++) {
                    float ltx = fmaxf(sg[m][0], ax1), lty = fmaxf(sg[m][1], ay1);
                    float rbx = fminf(sg[m][2], ax2), rby = fminf(sg[m][3], ay2);
                    float wx = fmaxf(rbx - ltx, 0.0f), wy = fmaxf(rby - lty, 0.0f);
                    float inter = wx * wy;
                    float iou = inter / (sg[m][4] + aarea - inter + 1e-10f);
                    if (iou > best) { best = iou; bm = m; }   // strict >: first m wins ties
                }
                // NO force-match here: applied as deltas in k_final (<=320 anchors).
                int code = (best < NEG_TH) ? 0 : (best < POS_TH) ? -1 : bm + 1;
                if (code > 0) {
                    pcnt++;
                    size_t ia = (size_t)bs * NA + a;
                    float mx1 = sg[bm][0], my1 = sg[bm][1], mx2 = sg[bm][2], my2 = sg[bm][3];
                    float g0 = ((mx1 + mx2) * 0.5f - cf.x) / (0.1f * cf.z);
                    float g1 = ((my1 + my2) * 0.5f - cf.y) / (0.1f * cf.w);
                    float g2 = logf(fmaxf(mx2 - mx1, 1e-6f) / cf.z) / 0.2f;
                    float g3 = logf(fmaxf(my2 - my1, 1e-6f) / cf.w) / 0.2f;
                    float4 p = ((const float4*)ploc)[ia];
                    float n0 = fabsf(p.x - g0), n1 = fabsf(p.y - g1);
                    float n2 = fabsf(p.z - g2), n3 = fabsf(p.w - g3);
                    float s0 = n0 < SL1B ? 0.5f * n0 * n0 / SL1B : n0 - 0.5f * SL1B;
                    float s1 = n1 < SL1B ? 0.5f * n1 * n1 / SL1B : n1 - 0.5f * SL1B;
                    float s2 = n2 < SL1B ? 0.5f * n2 * n2 / SL1B : n2 - 0.5f * SL1B;
                    float s3 = n3 < SL1B ? 0.5f * n3 * n3 / SL1B : n3 - 0.5f * SL1B;
                    regsum += s0 + s1 + s2 + s3;
                    int q = atomicAdd(&npq, 1);
                    qpos[q] = ((unsigned)bm << 16) | (unsigned)al;
                } else if (code == -1) {
                    int q = atomicAdd(&nqi, 1);
                    qign[q] = (unsigned)al;
                }
            }
            __syncthreads();

            // positive y==1 corrections (cooperative, coalesced 320B rows)
            float corrsum = 0.0f;
            int nq = npq, ni = nqi;
            for (int i = t; i < nq * 20; i += 256) {
                int qq = i / 20, c4 = i % 20;
                unsigned e = qpos[qq];
                int al = e & 0xFFFFu;
                int m  = (int)(e >> 16);
                float4 y4 = ((const float4*)(gtl + ((size_t)(bs * NM + m)) * NC))[c4];
                if (y4.x > 0.5f || y4.y > 0.5f || y4.z > 0.5f || y4.w > 0.5f) {
                    float4 x4 = ((const float4*)logits)[((size_t)bs * NA + a0 + al) * (NC / 4) + c4];
                    float yv[4] = {y4.x, y4.y, y4.z, y4.w};
                    float xv[4] = {x4.x, x4.y, x4.z, x4.w};
                    #pragma unroll
                    for (int j = 0; j < 4; j++) {
                        if (yv[j] > 0.5f) {
                            float x = xv[j];
                            float ee = __expf(-x);
                            float s = 1.0f + ee;
                            float pr = __builtin_amdgcn_rcpf(s);
                            float ls = __logf(s);
                            corrsum += ls * wsh[c4 * 4 + j] * (ee * pr)
                                     - OMB * (x + ls) * pr;
                        }
                    }
                }
            }
            // ignored rows: subtract from the maskless total (cooperative, coalesced)
            float negsum = 0.0f;
            for (int i = t; i < ni * 20; i += 256) {
                int qq = i / 20, c4 = i % 20;
                int al = (int)qign[qq];
                float4 x4 = ((const float4*)logits)[((size_t)bs * NA + a0 + al) * (NC / 4) + c4];
                float xv[4] = {x4.x, x4.y, x4.z, x4.w};
                float rs = 0.0f;
                #pragma unroll
                for (int j = 0; j < 4; j++) {
                    float x = xv[j];
                    float e = __expf(-x);
                    float s = 1.0f + e;
                    float pr = __builtin_amdgcn_rcpf(s);
                    float ls = __logf(s);
                    rs += (x + ls) * pr;
                }
                negsum += rs;
            }
            float clssum = corrsum - OMB * negsum;

            #pragma unroll
            for (int off = 32; off > 0; off >>= 1) {
                regsum += __shfl_xor(regsum, off);
                clssum += __shfl_xor(clssum, off);
                pcnt   += __shfl_xor(pcnt, off);
            }
            if (lane == 0) { sf[wave] = regsum; sc[wave] = clssum; si[wave] = pcnt; }
            __syncthreads();
            if (t == 0) {
                accReg = (double)(sf[0] + sf[1] + sf[2] + sf[3]);
                accCls = (double)(sc[0] + sc[1] + sc[2] + sc[3]);
                accNp  = si[0] + si[1] + si[2] + si[3];
            }
        }
    }

    // unconditional per-block result write -> no workspace init needed
    if (t == 0) { regp[bid] = accReg; clsp[bid] = accCls; npp[bid] = accNp; }
}

// ===================== kernel 2: reduce + force-match fixup + ego + combine ===========
__global__ void __launch_bounds__(256)
k_final(const float* __restrict__ gtb, const int* __restrict__ counts,
        const float* __restrict__ anchors, const float* __restrict__ ploc,
        const float* __restrict__ gtl, const float* __restrict__ logits,
        const int* __restrict__ cls_num,
        const unsigned long long* __restrict__ chunkbest,
        const double* __restrict__ regp, const double* __restrict__ clsp,
        const int* __restrict__ npp,
        const float* __restrict__ ego_preds, const int* __restrict__ ego_labels,
        float* __restrict__ out) {
    __shared__ float sg2[NBS][NM][5];
    __shared__ unsigned sA2[NBS][NM];
    __shared__ int scnt2[NBS];
    __shared__ float wsh[NC];
    __shared__ float wsum_sh;
    __shared__ float scol2[NCE];
    __shared__ float sdr[256], sdc[256];
    __shared__ int sdn[256];
    __shared__ float sred2[256];
    __shared__ int sval2[256];
    __shared__ double spr[4], spc[4];
    __shared__ int spn[4];
    const float EPSF = 1e-7f;
    int t = threadIdx.x;
    int wave = t >> 6, lane = t & 63;

    if (t < NBS) scnt2[t] = counts[t];
    if (t < NC) {
        float n = (float)cls_num[t];
        wsh[t] = OMB / (1.0f - powf(0.9999f, n));
    }
    if (t < NCE) {
        float c = 0.0f;
        for (int i = 0; i < NBS; i++) {
            int l = ego_labels[i];
            if (l > -1 && l == t) c = 1.0f;
        }
        scol2[t] = c;
    }
    __syncthreads();
    // gt boxes + per-gt global best anchor (reduce chunkbest over CPB chunks)
    for (int p = t; p < NBS * NM; p += 256) {
        int bs = p / NM, m = p % NM;
        const float* g = gtb + (size_t)p * 4;
        float x1 = g[0], y1 = g[1], x2 = g[2], y2 = g[3];
        sg2[bs][m][0] = x1; sg2[bs][m][1] = y1; sg2[bs][m][2] = x2; sg2[bs][m][3] = y2;
        sg2[bs][m][4] = (x2 - x1) * (y2 - y1);
        unsigned amin = 0xFFFFFFFFu;
        if (m < scnt2[bs]) {
            unsigned long long k = 0ULL;
            for (int c = 0; c < CPB; c++) {
                unsigned long long o = chunkbest[((size_t)(bs * CPB + c)) * NM + m];
                if (o > k) k = o;
            }
            amin = 0xFFFFFFFFu - (unsigned)(k & 0xFFFFFFFFull);
        }
        sA2[bs][m] = amin;
    }
    if (t == 0) {
        float s = 0.0f;
        for (int c = 0; c < NC; c++) s += wsh[c];
        wsum_sh = s;
    }
    __syncthreads();
    if (t < NC) wsh[t] = wsh[t] / wsum_sh;
    __syncthreads();

    // reduce the per-block partials
    double pr_ = 0.0, pc_ = 0.0; int pn_ = 0;
    for (int i = t; i < NUNITS; i += 256) { pr_ += regp[i]; pc_ += clsp[i]; pn_ += npp[i]; }
    #pragma unroll
    for (int off = 32; off > 0; off >>= 1) {
        pr_ += __shfl_xor(pr_, off);
        pc_ += __shfl_xor(pc_, off);
        pn_ += __shfl_xor(pn_, off);
    }
    if (lane == 0) { spr[wave] = pr_; spc[wave] = pc_; spn[wave] = pn_; }

    // ---- force-match deltas over ALL 320 (bs,m) pairs ----
    float dreg = 0.0f, dcls = 0.0f; int dnp = 0;
    for (int p = t; p < NBS * NM; p += 256) {
        int bs = p / NM, m = p % NM;
        int cnt = scnt2[bs];
        if (m < cnt) {
            unsigned a = sA2[bs][m];
            bool overridden = false;                       // later gt claiming same anchor wins
            for (int m2 = m + 1; m2 < cnt; m2++)
                if (sA2[bs][m2] == a) overridden = true;
            if (!overridden) {
                float4 cf = ((const float4*)anchors)[a];
                float ax1 = cf.x - cf.z * 0.5f, ay1 = cf.y - cf.w * 0.5f;
                float ax2 = cf.x + cf.z * 0.5f, ay2 = cf.y + cf.w * 0.5f;
                float aarea = (ax2 - ax1) * (ay2 - ay1);
                float best = -1.0f; int bm = 0;
                for (int m2 = 0; m2 < cnt; m2++) {
                    float ltx = fmaxf(sg2[bs][m2][0], ax1), lty = fmaxf(sg2[bs][m2][1], ay1);
                    float rbx = fminf(sg2[bs][m2][2], ax2), rby = fminf(sg2[bs][m2][3], ay2);
                    float wx = fmaxf(rbx - ltx, 0.0f), wy = fmaxf(rby - lty, 0.0f);
                    float inter = wx * wy;
                    float iou = inter / (sg2[bs][m2][4] + aarea - inter + 1e-10f);
                    if (iou > best) { best = iou; bm = m2; }
                }
                int code = (best < NEG_TH) ? 0 : (best < POS_TH) ? -1 : bm + 1;
                if (!(code > 0 && bm == m)) {             // identical match -> no-op
                    size_t ia = (size_t)bs * NA + a;
                    float4 pv = ((const float4*)ploc)[ia];
                    auto sl1 = [&](int mm) -> float {      // bit-identical to role1's formula
                        float mx1 = sg2[bs][mm][0], my1 = sg2[bs][mm][1];
                        float mx2 = sg2[bs][mm][2], my2 = sg2[bs][mm][3];
                        float g0 = ((mx1 + mx2) * 0.5f - cf.x) / (0.1f * cf.z);
                        float g1 = ((my1 + my2) * 0.5f - cf.y) / (0.1f * cf.w);
                        float g2 = logf(fmaxf(mx2 - mx1, 1e-6f) / cf.z) / 0.2f;
                        float g3 = logf(fmaxf(my2 - my1, 1e-6f) / cf.w) / 0.2f;
                        float n0 = fabsf(pv.x - g0), n1 = fabsf(pv.y - g1);
                        float n2 = fabsf(pv.z - g2), n3 = fabsf(pv.w - g3);
                        float s0 = n0 < SL1B ? 0.5f * n0 * n0 / SL1B : n0 - 0.5f * SL1B;
                        float s1 = n1 < SL1B ? 0.5f * n1 * n1 / SL1B : n1 - 0.5f * SL1B;
                        float s2 = n2 < SL1B ? 0.5f * n2 * n2 / SL1B : n2 - 0.5f * SL1B;
                        float s3 = n3 < SL1B ? 0.5f * n3 * n3 / SL1B : n3 - 0.5f * SL1B;
                        return s0 + s1 + s2 + s3;
                    };
                    dreg += sl1(m);                        // new positive (idx m)
                    if (code > 0) dreg -= sl1(bm);         // was positive with other gt
                    else dnp += 1;                         // background/ignored -> positive
                    const float* xrow = logits + ia * NC;
                    const float* ynew = gtl + ((size_t)(bs * NM + m)) * NC;
                    const float* yold = gtl + ((size_t)(bs * NM + bm)) * NC;
                    bool addbg = (code == -1);             // row was subtracted by role1
                    for (int c = 0; c < NC; c++) {
                        float x = xrow[c];
                        float e = __expf(-x);
                        float s = 1.0f + e;
                        float pr = __builtin_amdgcn_rcpf(s);
                        float ls = __logf(s);
                        float bgterm = OMB * (x + ls) * pr;
                        if (addbg) dcls += bgterm;         // re-add row to background total
                        if (ynew[c] > 0.5f)
                            dcls += ls * wsh[c] * (e * pr) - bgterm;
                        if (code > 0 && yold[c] > 0.5f)
                            dcls -= ls * wsh[c] * (e * pr) - bgterm;
                    }
                }
            }
        }
    }
    sdr[t] = dreg; sdc[t] = dcls; sdn[t] = dnp;

    // ---- ego focal loss ----
    float term = 0.0f;
    if (t < NBS * NCE) {
        int bs = t / NCE, e = t % NCE;
        int lbl = ego_labels[bs];
        if (lbl > -1) {
            float x = ego_preds[t];
            float ep = 1.0f / (1.0f + expf(-x));
            float oh = scol2[e];
            float af = 0.25f * oh + 0.75f * (1.0f - oh);
            float ept = ep * oh + (1.0f - ep) * (1.0f - oh);
            float epc = fminf(fmaxf(ep, EPSF), 1.0f - EPSF);
            float bce = -(oh * logf(epc) + (1.0f - oh) * log1pf(-epc));
            float om = 1.0f - ept;
            term = bce * af * om * om;
        }
    }
    sred2[t] = term;
    sval2[t] = (t < NBS && ego_labels[t] > -1) ? 1 : 0;
    __syncthreads();
    for (int off = 128; off > 0; off >>= 1) {
        if (t < off) {
            sdr[t] += sdr[t + off]; sdc[t] += sdc[t + off]; sdn[t] += sdn[t + off];
            sred2[t] += sred2[t + off]; sval2[t] += sval2[t + off];
        }
        __syncthreads();
    }
    if (t == 0) {
        float esum = sred2[0];
        int ne = sval2[0];
        float ego = (ne > 0) ? esum / (float)(ne > 1 ? ne : 1) : 0.0f;
        double regT = (spr[0] + spr[1] + spr[2] + spr[3]) + (double)sdr[0];
        double clsT = (spc[0] + spc[1] + spc[2] + spc[3]) + (double)sdc[0];
        double npd = (double)((spn[0] + spn[1] + spn[2] + spn[3]) + sdn[0]);
        if (npd < 1.0) npd = 1.0;
        out[0] = (float)(regT / (npd * 4.0));
        out[1] = (float)(clsT / npd / 8.0 + (double)ego / 4.0);
    }
}

// ---------------- host launch: TWO dispatches, one edge, no init ----------------
extern "C" void kernel_launch(void* const* d_in, const int* in_sizes, int n_in,
                              void* d_out, int out_size, void* d_ws, size_t ws_size,
                              hipStream_t stream) {
    const float* confidence = (const float*)d_in[0];
    const float* ploc       = (const float*)d_in[1];
    const float* gtb        = (const float*)d_in[2];
    const float* gtl        = (const float*)d_in[3];
    const int*   counts     = (const int*)d_in[4];
    const float* anchors    = (const float*)d_in[5];
    const float* ego_preds  = (const float*)d_in[6];
    const int*   ego_labels = (const int*)d_in[7];
    const int*   cls_num    = (const int*)d_in[8];
    float* out = (float*)d_out;

    // workspace (every slot written before read -> poisoned ws is fine):
    // [chunkbest 1200*20 u64 = 192000 | regp 3600 f64 = 28800 | clsp 28800 | npp 14400]
    char* ws = (char*)d_ws;
    unsigned long long* chunkbest = (unsigned long long*)ws;
    double* regp = (double*)(ws + 192000);
    double* clsp = (double*)(ws + 220800);
    int*    npp  = (int*)(ws + 249600);

    k_mega<<<NUNITS, 256, 0, stream>>>(gtb, counts, anchors, ploc, gtl, confidence,
                                       cls_num, chunkbest, regp, clsp, npp);
    k_final<<<1, 256, 0, stream>>>(gtb, counts, anchors, ploc, gtl, confidence,
                                   cls_num, chunkbest, regp, clsp, npp,
                                   ego_preds, ego_labels, out);
}